// Round 2
// baseline (69.879 us; speedup 1.0000x reference)
//
#include <hip/hip_runtime.h>
#include <math.h>

// Problem constants (from reference): x[B][L][D] fp32
#define B 8
#define L 4096
#define D 512
#define LC 128              // chunk length
#define CK (L / LC)         // 32 chunks
#define BLD ((size_t)B * L * D)

// ws layout (floats):
//   phz  [D][2]            offset 0
//   pi   [D][2]            offset 2*D
//   Ptab [CK][D][2]        offset 4*D          (Ptab[k][d] = phazor[d]^(k*LC), fp64-exact)
//   le   [B][CK][D][2]     offset 4*D + 2*CK*D (chunk-local scan ends)
#define WS_PHZ   0
#define WS_PI    (2 * D)
#define WS_PTAB  (4 * D)
#define WS_LE    (4 * D + 2 * CK * D)
#define WS_FLOATS (WS_LE + 2 * B * CK * D)

__global__ __launch_bounds__(256) void setup_k(const float* __restrict__ pinit,
                                               const float* __restrict__ pparam,
                                               float* __restrict__ ws) {
    int d = blockIdx.x * blockDim.x + threadIdx.x;
    if (d >= D) return;
    float a = pparam[d * 2 + 0];
    float bb = pparam[d * 2 + 1];
    double r2 = (double)a * (double)a + (double)bb * (double)bb;
    double th = atan2((double)bb, (double)a);
    double mag = exp(-r2);
    ws[WS_PHZ + d * 2 + 0] = (float)(mag * cos(th));
    ws[WS_PHZ + d * 2 + 1] = (float)(mag * sin(th));
    ws[WS_PI + d * 2 + 0] = pinit[d * 2 + 0];
    ws[WS_PI + d * 2 + 1] = pinit[d * 2 + 1];
    float* P = ws + WS_PTAB;
    for (int c = 0; c < CK; ++c) {
        double t = (double)(c * LC);
        double e = exp(-t * r2);
        double ang = t * th;
        P[(c * D + d) * 2 + 0] = (float)(e * cos(ang));
        P[(c * D + d) * 2 + 1] = (float)(e * sin(ang));
    }
}

// Pass 1: chunk-local scan with zero carry-in; store final state per (b, chunk, d).
__global__ __launch_bounds__(256) void pass1_k(const float* __restrict__ x,
                                               const float* __restrict__ ws,
                                               float* __restrict__ le) {
    int idx = blockIdx.x * blockDim.x + threadIdx.x;   // b*CK*D + c*D + d
    int d = idx % D;
    int c = (idx / D) % CK;
    int b = idx / (D * CK);
    float pr = ws[WS_PHZ + d * 2 + 0];
    float pim = ws[WS_PHZ + d * 2 + 1];
    float ur = 0.f, ui = 0.f;
    const float* xp = x + ((size_t)b * L + (size_t)c * LC) * D + d;
#pragma unroll 8
    for (int i = 0; i < LC; ++i) {
        float xv = xp[(size_t)i * D];
        float nr = fmaf(pr, ur, fmaf(-pim, ui, xv));
        float ni = fmaf(pr, ui, pim * ur);
        ur = nr;
        ui = ni;
    }
    le[(size_t)idx * 2 + 0] = ur;
    le[(size_t)idx * 2 + 1] = ui;
}

// Pass 2: rebuild carry-in from previous chunks' ends via the exact power table,
// re-scan the chunk, write outputs.
// MODE 0: out = [real plane][real plane]   (harness cast complex64 -> float32)
// MODE 1: out = [real plane][interleaved (re,im) plane]
template <int MODE>
__global__ __launch_bounds__(256) void pass2_k(const float* __restrict__ x,
                                               const float* __restrict__ hr,
                                               const float* __restrict__ hi,
                                               const float* __restrict__ ws,
                                               const float* __restrict__ le,
                                               float* __restrict__ out) {
    int idx = blockIdx.x * blockDim.x + threadIdx.x;   // b*CK*D + c*D + d
    int d = idx % D;
    int c = (idx / D) % CK;
    int b = idx / (D * CK);

    float pr = ws[WS_PHZ + d * 2 + 0];
    float pim = ws[WS_PHZ + d * 2 + 1];
    float qr = ws[WS_PI + d * 2 + 0];
    float qi = ws[WS_PI + d * 2 + 1];
    const float* P = ws + WS_PTAB;

    // carry-in W[c] = sum_{j<c} phazor^{(c-1-j)*LC} * le[b][j][d]
    float ur = 0.f, ui = 0.f;
    for (int j = 0; j < c; ++j) {
        int k = c - 1 - j;
        float Pr = P[(k * D + d) * 2 + 0];
        float Pi = P[(k * D + d) * 2 + 1];
        float lr = le[(((size_t)b * CK + j) * D + d) * 2 + 0];
        float li = le[(((size_t)b * CK + j) * D + d) * 2 + 1];
        ur = fmaf(Pr, lr, fmaf(-Pi, li, ur));
        ui = fmaf(Pr, li, fmaf(Pi, lr, ui));
    }

    // pw = phazor^(c*LC + 1) = Ptab[c] * phazor
    float Pcr = P[(c * D + d) * 2 + 0];
    float Pci = P[(c * D + d) * 2 + 1];
    float pwr = Pcr * pr - Pci * pim;
    float pwi = fmaf(Pcr, pim, Pci * pr);

    float hre = hr[b * D + d];
    float him = hi[b * D + d];

    const float* xp = x + ((size_t)b * L + (size_t)c * LC) * D + d;
    float* outr = out + ((size_t)b * L + (size_t)c * LC) * D + d;
    float* outr2 = outr + BLD;                                  // MODE 0 second plane
    float2* outc = (float2*)(out + BLD) + ((size_t)b * L + (size_t)c * LC) * D + d;

#pragma unroll 4
    for (int i = 0; i < LC; ++i) {
        float xv = xp[(size_t)i * D];
        float nr = fmaf(pr, ur, fmaf(-pim, ui, xv));
        float ni = fmaf(pr, ui, pim * ur);
        ur = nr;
        ui = ni;
        // val = pi*u + hidden*pw
        float vr = fmaf(qr, ur, fmaf(-qi, ui, fmaf(hre, pwr, -him * pwi)));
        float vi = fmaf(qr, ui, fmaf(qi, ur, fmaf(hre, pwi, him * pwr)));
        outr[(size_t)i * D] = vr;
        if (MODE == 0) {
            outr2[(size_t)i * D] = vr;
        } else {
            outc[(size_t)i * D] = make_float2(vr, vi);
        }
        // pw *= phazor
        float tr = fmaf(pwr, pr, -pwi * pim);
        float ti = fmaf(pwr, pim, pwi * pr);
        pwr = tr;
        pwi = ti;
    }
}

// Fallback (no scratch needed): one thread per (b,d), full-L scan. Coalesced
// across d; low parallelism but correct. Used only if ws_size is too small.
template <int MODE>
__global__ __launch_bounds__(256) void fallback_k(const float* __restrict__ x,
                                                  const float* __restrict__ hr,
                                                  const float* __restrict__ hi,
                                                  const float* __restrict__ pinit,
                                                  const float* __restrict__ pparam,
                                                  float* __restrict__ out) {
    int idx = blockIdx.x * blockDim.x + threadIdx.x;   // b*D + d
    if (idx >= B * D) return;
    int d = idx % D;
    int b = idx / D;
    float a = pparam[d * 2 + 0];
    float bb = pparam[d * 2 + 1];
    double r2 = (double)a * (double)a + (double)bb * (double)bb;
    double th = atan2((double)bb, (double)a);
    double mag = exp(-r2);
    float pr = (float)(mag * cos(th));
    float pim = (float)(mag * sin(th));
    float qr = pinit[d * 2 + 0];
    float qi = pinit[d * 2 + 1];
    float hre = hr[b * D + d];
    float him = hi[b * D + d];
    float ur = 0.f, ui = 0.f;
    float pwr = pr, pwi = pim;                     // phazor^(t+1), t=0
    const float* xp = x + (size_t)b * L * D + d;
    float* outr = out + (size_t)b * L * D + d;
    float* outr2 = outr + BLD;
    float2* outc = (float2*)(out + BLD) + (size_t)b * L * D + d;
    for (int t = 0; t < L; ++t) {
        float xv = xp[(size_t)t * D];
        float nr = fmaf(pr, ur, fmaf(-pim, ui, xv));
        float ni = fmaf(pr, ui, pim * ur);
        ur = nr; ui = ni;
        float vr = fmaf(qr, ur, fmaf(-qi, ui, fmaf(hre, pwr, -him * pwi)));
        float vi = fmaf(qr, ui, fmaf(qi, ur, fmaf(hre, pwi, him * pwr)));
        outr[(size_t)t * D] = vr;
        if (MODE == 0) outr2[(size_t)t * D] = vr;
        else outc[(size_t)t * D] = make_float2(vr, vi);
        float tr = fmaf(pwr, pr, -pwi * pim);
        float ti = fmaf(pwr, pim, pwi * pr);
        pwr = tr; pwi = ti;
    }
}

extern "C" void kernel_launch(void* const* d_in, const int* in_sizes, int n_in,
                              void* d_out, int out_size, void* d_ws, size_t ws_size,
                              hipStream_t stream) {
    const float* x = (const float*)d_in[0];
    const float* hreal = (const float*)d_in[1];
    const float* himag = (const float*)d_in[2];
    const float* pinit = (const float*)d_in[3];
    const float* pparam = (const float*)d_in[4];
    float* ws = (float*)d_ws;
    float* out = (float*)d_out;

    const int mode = (out_size >= (int)(3 * BLD)) ? 1 : 0;
    const bool fast = ws_size >= (size_t)WS_FLOATS * sizeof(float);

    if (fast) {
        float* le = ws + WS_LE;
        setup_k<<<(D + 255) / 256, 256, 0, stream>>>(pinit, pparam, ws);
        int n = B * CK * D;                       // 131072 threads
        pass1_k<<<n / 256, 256, 0, stream>>>(x, ws, le);
        if (mode == 0)
            pass2_k<0><<<n / 256, 256, 0, stream>>>(x, hreal, himag, ws, le, out);
        else
            pass2_k<1><<<n / 256, 256, 0, stream>>>(x, hreal, himag, ws, le, out);
    } else {
        int n = B * D;                            // 4096 threads
        if (mode == 0)
            fallback_k<0><<<(n + 255) / 256, 256, 0, stream>>>(x, hreal, himag, pinit, pparam, out);
        else
            fallback_k<1><<<(n + 255) / 256, 256, 0, stream>>>(x, hreal, himag, pinit, pparam, out);
    }
}